// Round 3
// baseline (160.930 us; speedup 1.0000x reference)
//
#include <hip/hip_runtime.h>

#define DIM   400
#define D4    100
#define B     32
#define NCAND 14505
#define CT    32      // candidates per ctile
#define NCT   454     // ceil(NCAND/CT)
#define THREADS 256

// ---- fused setup ----
// blocks 0..31 : out[b][:] = base[b] = one + 0.98*sum(o[b])
// blocks 32..63: qg[b][:]  = ent[head_b] + relc[rel_b]     (only when ws available)
__global__ void setup_kernel(const float* __restrict__ ent,
                             const float* __restrict__ relc,
                             const float* __restrict__ relo,
                             const float* __restrict__ onev,
                             const int*   __restrict__ pairs,
                             float* __restrict__ qg,
                             float* __restrict__ out) {
    const int b    = blockIdx.x & 31;
    const int role = blockIdx.x >> 5;
    const int tid  = threadIdx.x;
    const int r    = pairs[b * 2 + 1];
    if (role == 0) {
        float so = 0.f;
        for (int i = tid; i < DIM; i += THREADS) so += relo[r * DIM + i];
        __shared__ float sred[THREADS / 64];
        for (int off = 32; off; off >>= 1) so += __shfl_down(so, off);
        if ((tid & 63) == 0) sred[tid >> 6] = so;
        __syncthreads();
        const float base = onev[0] + 0.98f * (sred[0] + sred[1] + sred[2] + sred[3]);
        float4 b4 = make_float4(base, base, base, base);
        float4* o4 = (float4*)(out + (size_t)b * NCAND);
        for (int i = tid; i < NCAND / 4; i += THREADS) o4[i] = b4;   // 3626 f4 = 14504
        if (tid == 0) out[(size_t)b * NCAND + NCAND - 1] = base;
    } else {
        if (!qg) return;
        const int h = pairs[b * 2 + 0];
        const float4* h4 = (const float4*)(ent  + (size_t)h * DIM);
        const float4* c4 = (const float4*)(relc + (size_t)r * DIM);
        float4* q4 = (float4*)(qg + (size_t)b * DIM);
        for (int i = tid; i < D4; i += THREADS) {
            float4 a = h4[i], c = c4[i];
            q4[i] = make_float4(a.x + c.x, a.y + c.y, a.z + c.z, a.w + c.w);
        }
    }
}

// ---- main: register-tiled, LDS-free inner loop ----
// thread = (cand 32, bq 4, s 2); slice j = g*2+s covers f4 [j*25, j*25+25)
// grid 912 = 8 XCD residues * 114; ct = r + 8*(k%57), g = k/57  (same-ct blocks -> same XCD L2)
template <bool USE_WS>
__global__ __launch_bounds__(THREADS, 4)
void score_kernel(const float* __restrict__ ent,
                  const float* __restrict__ relc,
                  const float* __restrict__ relo,
                  const int*   __restrict__ pairs,
                  const int*   __restrict__ cidx,
                  const float* __restrict__ qg,
                  float* __restrict__ out) {
    const int fid  = blockIdx.x;
    const int rx   = fid & 7;
    const int k    = fid >> 3;
    const int ct   = rx + 8 * (k % 57);
    const int g    = k / 57;                  // 0 or 1
    if (ct >= NCT) return;

    const int tid  = threadIdx.x;
    const int cand = tid & 31;
    const int bq   = (tid >> 5) & 3;
    const int s    = tid >> 7;                // 0 or 1
    const int j    = g * 2 + s;               // slice 0..3
    const int f0   = j * 25;                  // float4 base in row
    const int b0   = bq * 8;

    const int gn = ct * CT + cand;
    const int ci = cidx[gn < NCAND ? gn : NCAND - 1];
    const float4* crow = (const float4*)(ent + (size_t)ci * DIM) + f0;

    // per-batch row byte offsets (static arrays, unrolled indexing only)
    size_t off_o[8], off_q[8], off_h[8], off_rc[8];
#pragma unroll
    for (int b = 0; b < 8; ++b) {
        const int rb = pairs[(b0 + b) * 2 + 1];
        off_o[b] = (size_t)rb * (DIM * 4);
        if (USE_WS) {
            off_q[b] = (size_t)(b0 + b) * (DIM * 4);
        } else {
            const int hb = pairs[(b0 + b) * 2 + 0];
            off_h[b]  = (size_t)hb * (DIM * 4);
            off_rc[b] = (size_t)rb * (DIM * 4);
        }
    }

    float am[8], ad[8];
#pragma unroll
    for (int b = 0; b < 8; ++b) { am[b] = 0.f; ad[b] = 0.f; }

    for (int ch = 0; ch < 5; ++ch) {          // 5 chunks x 5 f4 = 25 f4 = 100 dims
        float4 c[5];
#pragma unroll
        for (int u = 0; u < 5; ++u) c[u] = crow[ch * 5 + u];

#pragma unroll
        for (int b = 0; b < 8; ++b) {
            const float4* op = (const float4*)((const char*)relo + off_o[b]) + f0 + ch * 5;
            const float4* qp = nullptr;
            const float4* hp = nullptr;
            const float4* rp = nullptr;
            if (USE_WS) {
                qp = (const float4*)((const char*)qg + off_q[b]) + f0 + ch * 5;
            } else {
                hp = (const float4*)((const char*)ent  + off_h[b])  + f0 + ch * 5;
                rp = (const float4*)((const char*)relc + off_rc[b]) + f0 + ch * 5;
            }
#pragma unroll
            for (int u = 0; u < 5; ++u) {
                float4 o = op[u];
                float4 q;
                if (USE_WS) {
                    q = qp[u];
                } else {
                    float4 a = hp[u], cc = rp[u];
                    q = make_float4(a.x + cc.x, a.y + cc.y, a.z + cc.z, a.w + cc.w);
                }
                float dx = fabsf(c[u].x - q.x);
                float dy = fabsf(c[u].y - q.y);
                float dz = fabsf(c[u].z - q.z);
                float dw = fabsf(c[u].w - q.w);
                am[b] += fmaxf(dx, o.x); ad[b] += dx;
                am[b] += fmaxf(dy, o.y); ad[b] += dy;
                am[b] += fmaxf(dz, o.z); ad[b] += dz;
                am[b] += fmaxf(dw, o.w); ad[b] += dw;
            }
        }
    }

    // ---- block reduce across the 2 in-block slices, then 1 atomic per (out, slice-group) ----
    __shared__ float red[2][CT][B + 1];       // 8.4 KB, stride 33 -> conflict-free
#pragma unroll
    for (int b = 0; b < 8; ++b)
        red[s][cand][b0 + b] = -0.98f * am[b] - 0.02f * ad[b];
    __syncthreads();

#pragma unroll
    for (int kk = 0; kk < 4; ++kk) {
        const int idx = tid * 4 + kk;         // 1024 outputs per block
        const int c2  = idx & 31;
        const int b2  = idx >> 5;
        const int g2  = ct * CT + c2;
        if (g2 < NCAND)
            atomicAdd(out + (size_t)b2 * NCAND + g2, red[0][c2][b2] + red[1][c2][b2]);
    }
}

extern "C" void kernel_launch(void* const* d_in, const int* in_sizes, int n_in,
                              void* d_out, int out_size, void* d_ws, size_t ws_size,
                              hipStream_t stream) {
    const float* ent   = (const float*)d_in[0];
    const float* relc  = (const float*)d_in[1];
    const float* relo  = (const float*)d_in[2];
    const float* onev  = (const float*)d_in[3];
    const int*   pairs = (const int*)d_in[4];
    const int*   cidx  = (const int*)d_in[5];
    float*       out   = (float*)d_out;

    const size_t need = (size_t)B * DIM * sizeof(float);   // 51.2 KB for q
    const bool use_ws = ws_size >= need;
    float* qg = use_ws ? (float*)d_ws : nullptr;

    setup_kernel<<<use_ws ? 64 : 32, THREADS, 0, stream>>>(ent, relc, relo, onev, pairs, qg, out);

    const int grid = 8 * 57 * 2;   // 912 (4 pad blocks exit early)
    if (use_ws)
        score_kernel<true><<<grid, THREADS, 0, stream>>>(ent, relc, relo, pairs, cidx, qg, out);
    else
        score_kernel<false><<<grid, THREADS, 0, stream>>>(ent, relc, relo, pairs, cidx, nullptr, out);
}

// Round 4
// 47.939 us; speedup vs baseline: 3.3570x; 3.3570x over previous
//
#include <hip/hip_runtime.h>

#define DIM     400
#define D4      100
#define B       32
#define NCAND   14505
#define NCT     227     // ceil(NCAND / 64)
#define THREADS 256

// ---- setup (ws path): qg[b] = ent[head_b] + relc[rel_b]; baseg[b] = one + 0.98*sum(relo[rel_b])
__global__ void setup_kernel(const float* __restrict__ ent,
                             const float* __restrict__ relc,
                             const float* __restrict__ relo,
                             const float* __restrict__ onev,
                             const int*   __restrict__ pairs,
                             float* __restrict__ qg,
                             float* __restrict__ baseg) {
    const int b   = blockIdx.x;
    const int tid = threadIdx.x;
    const int h = pairs[b * 2 + 0];
    const int r = pairs[b * 2 + 1];
    const float4* h4 = (const float4*)(ent  + (size_t)h * DIM);
    const float4* c4 = (const float4*)(relc + (size_t)r * DIM);
    const float4* o4 = (const float4*)(relo + (size_t)r * DIM);
    float4* q4 = (float4*)(qg + (size_t)b * DIM);
    float so = 0.f;
    for (int i = tid; i < D4; i += THREADS) {
        float4 a = h4[i], c = c4[i], o = o4[i];
        q4[i] = make_float4(a.x + c.x, a.y + c.y, a.z + c.z, a.w + c.w);
        so += o.x + o.y + o.z + o.w;
    }
    __shared__ float sred[THREADS / 64];
    for (int off = 32; off; off >>= 1) so += __shfl_down(so, off);
    if ((tid & 63) == 0) sred[tid >> 6] = so;
    __syncthreads();
    if (tid == 0)
        baseg[b] = onev[0] + 0.98f * (sred[0] + sred[1] + sred[2] + sred[3]);
}

// ---- main: thread owns (1 cand x 2 batches x all 400 dims). No LDS, no atomics. ----
// grid: fid = xcd + 8*(bt + 4*g), ct = xcd + 8*g  -> all 4 btiles of a ctile on one XCD,
// per-XCD candidate working set ~2.9 MB (L2-resident).
template <bool USE_WS>
__global__ __launch_bounds__(THREADS)
void score_kernel(const float* __restrict__ ent,
                  const float* __restrict__ relc,
                  const float* __restrict__ relo,
                  const float* __restrict__ onev,
                  const int*   __restrict__ pairs,
                  const int*   __restrict__ cidx,
                  const float* __restrict__ qg,
                  const float* __restrict__ baseg,
                  float* __restrict__ out) {
    const int fid = blockIdx.x;
    const int xcd = fid & 7;
    const int k   = fid >> 3;
    const int bt  = k & 3;          // batch tile (8 batches)
    const int g   = k >> 2;         // 0..28
    const int ct  = xcd + 8 * g;    // candidate tile (64 cands)
    if (ct >= NCT) return;

    const int tid  = threadIdx.x;
    const int lane = tid & 63;
    // wave-uniform batch pair, forced into SGPR
    const int b0 = __builtin_amdgcn_readfirstlane(bt * 8 + (tid >> 6) * 2);
    const int b1 = b0 + 1;

    const int cand = ct * 64 + lane;
    const int cl   = cand < NCAND ? cand : NCAND - 1;
    const int ci   = cidx[cl];
    const float4* crow = (const float4*)(ent + (size_t)ci * DIM);

    const int r0 = pairs[b0 * 2 + 1];
    const int r1 = pairs[b1 * 2 + 1];
    const float4* o0p = (const float4*)(relo + (size_t)r0 * DIM);
    const float4* o1p = (const float4*)(relo + (size_t)r1 * DIM);
    const float4 *q0p = nullptr, *q1p = nullptr, *h0p = nullptr, *h1p = nullptr,
                 *c0p = nullptr, *c1p = nullptr;
    if (USE_WS) {
        q0p = (const float4*)(qg + (size_t)b0 * DIM);
        q1p = (const float4*)(qg + (size_t)b1 * DIM);
    } else {
        h0p = (const float4*)(ent  + (size_t)pairs[b0 * 2] * DIM);
        h1p = (const float4*)(ent  + (size_t)pairs[b1 * 2] * DIM);
        c0p = (const float4*)(relc + (size_t)r0 * DIM);
        c1p = (const float4*)(relc + (size_t)r1 * DIM);
    }

    float s0 = 0.f, s1 = 0.f;       // fused score accumulators
    float oa0 = 0.f, oa1 = 0.f;     // fallback: sum of o

#define ACC(cc, qq, oo, ss)                                        \
    {                                                              \
        float d_ = (cc) - (qq);                                    \
        float m_ = fmaxf(fabsf(d_), (oo));                         \
        ss = fmaf(-0.98f, m_, fmaf(-0.02f, fabsf(d_), ss));        \
    }

    for (int ch = 0; ch < 25; ++ch) {           // 25 chunks x 4 f4 = one 64B line/lane/chunk
        float4 c[4];
#pragma unroll
        for (int u = 0; u < 4; ++u) c[u] = crow[ch * 4 + u];

#pragma unroll
        for (int u = 0; u < 4; ++u) {
            const int i = ch * 4 + u;
            const float4 o0 = o0p[i];
            const float4 o1 = o1p[i];
            float4 q0, q1;
            if (USE_WS) {
                q0 = q0p[i];
                q1 = q1p[i];
            } else {
                float4 a0 = h0p[i], x0 = c0p[i];
                float4 a1 = h1p[i], x1 = c1p[i];
                q0 = make_float4(a0.x + x0.x, a0.y + x0.y, a0.z + x0.z, a0.w + x0.w);
                q1 = make_float4(a1.x + x1.x, a1.y + x1.y, a1.z + x1.z, a1.w + x1.w);
                oa0 += o0.x + o0.y + o0.z + o0.w;
                oa1 += o1.x + o1.y + o1.z + o1.w;
            }
            ACC(c[u].x, q0.x, o0.x, s0) ACC(c[u].y, q0.y, o0.y, s0)
            ACC(c[u].z, q0.z, o0.z, s0) ACC(c[u].w, q0.w, o0.w, s0)
            ACC(c[u].x, q1.x, o1.x, s1) ACC(c[u].y, q1.y, o1.y, s1)
            ACC(c[u].z, q1.z, o1.z, s1) ACC(c[u].w, q1.w, o1.w, s1)
        }
    }
#undef ACC

    float base0, base1;
    if (USE_WS) {
        base0 = baseg[b0];
        base1 = baseg[b1];
    } else {
        const float onec = onev[0];
        base0 = onec + 0.98f * oa0;
        base1 = onec + 0.98f * oa1;
    }

    if (cand < NCAND) {
        out[(size_t)b0 * NCAND + cand] = base0 + s0;
        out[(size_t)b1 * NCAND + cand] = base1 + s1;
    }
}

extern "C" void kernel_launch(void* const* d_in, const int* in_sizes, int n_in,
                              void* d_out, int out_size, void* d_ws, size_t ws_size,
                              hipStream_t stream) {
    const float* ent   = (const float*)d_in[0];
    const float* relc  = (const float*)d_in[1];
    const float* relo  = (const float*)d_in[2];
    const float* onev  = (const float*)d_in[3];
    const int*   pairs = (const int*)d_in[4];
    const int*   cidx  = (const int*)d_in[5];
    float*       out   = (float*)d_out;

    const int grid = 8 * 4 * 29;    // 928; blocks with ct>=227 exit early
    const size_t need = (size_t)(B * DIM + B) * sizeof(float);

    if (ws_size >= need) {
        float* qg    = (float*)d_ws;
        float* baseg = qg + (size_t)B * DIM;
        setup_kernel<<<B, THREADS, 0, stream>>>(ent, relc, relo, onev, pairs, qg, baseg);
        score_kernel<true><<<grid, THREADS, 0, stream>>>(
            ent, relc, relo, onev, pairs, cidx, qg, baseg, out);
    } else {
        score_kernel<false><<<grid, THREADS, 0, stream>>>(
            ent, relc, relo, onev, pairs, cidx, nullptr, nullptr, out);
    }
}